// Round 2
// baseline (1191.514 us; speedup 1.0000x reference)
//
#include <hip/hip_runtime.h>

// out[4096,128] = A[4096,49998] @ W[0:49998,128], all fp32 (bf16 MFMA inside)
#define M_ROWS 4096
#define K_EFF  49998
#define K_PAD  50048        // 782 * 64, zero-padded in Bt
#define N_EMB  128
#define BM     64
#define BK     64
#define S_SPLIT 16
#define IT_TOTAL 782        // ceil(K_EFF / BK)
#define OUT_ELEMS (M_ROWS * N_EMB)

typedef __attribute__((ext_vector_type(8))) short        short8;   // 8 bf16 (MFMA A/B frag)
typedef __attribute__((ext_vector_type(4))) float        floatx4;  // MFMA C/D frag
typedef __attribute__((ext_vector_type(2))) float        floatx2;
typedef __attribute__((ext_vector_type(4))) unsigned int uintx4;

__device__ __forceinline__ unsigned short f2bf(float f){
  // round-to-nearest-even fp32 -> bf16 (finite inputs)
  unsigned int u = __builtin_bit_cast(unsigned int, f);
  u += 0x7fffu + ((u >> 16) & 1u);
  return (unsigned short)(u >> 16);
}

// ---------------------------------------------------------------------------
// prep: build Bt [128][K_PAD] bf16 (k-contiguous per embed dim) from
// W [50000][128] fp32 (first 49998 rows), zero-pad the k tail, zero d_out.
// LDS transpose keeps both the global read and write coalesced.
// ---------------------------------------------------------------------------
__global__ void prep_bt(const float* __restrict__ W,
                        unsigned short* __restrict__ Bt,
                        float* __restrict__ out){
  __shared__ unsigned short T[64 * 132];
  const int tid = threadIdx.x;

  // zero the poisoned output; 782*256 threads >= 131072 float4
  const int gid = blockIdx.x * 256 + tid;
  if (gid < OUT_ELEMS / 4) ((floatx4*)out)[gid] = (floatx4)0.0f;

  const int kp0 = blockIdx.x * 64;

#pragma unroll
  for (int p = 0; p < 8; ++p){
    const int id = p * 256 + tid;
    const int r  = id >> 5;
    const int c4 = id & 31;
    const int kp = kp0 + r;
    floatx4 f = (floatx4)0.0f;
    if (kp < K_EFF) f = *(const floatx4*)(W + (size_t)kp * N_EMB + c4 * 4);
    *(unsigned int*)(&T[r * 132 + c4 * 4])     = f2bf(f.x) | ((unsigned)f2bf(f.y) << 16);
    *(unsigned int*)(&T[r * 132 + c4 * 4 + 2]) = f2bf(f.z) | ((unsigned)f2bf(f.w) << 16);
  }
  __syncthreads();

#pragma unroll
  for (int p = 0; p < 4; ++p){
    const int id = p * 256 + tid;
    const int n  = id >> 3;
    const int c  = id & 7;
    unsigned short v[8];
#pragma unroll
    for (int j = 0; j < 8; ++j) v[j] = T[(c * 8 + j) * 132 + n];
    uintx4 pk;
    pk.x = v[0] | ((unsigned)v[1] << 16);
    pk.y = v[2] | ((unsigned)v[3] << 16);
    pk.z = v[4] | ((unsigned)v[5] << 16);
    pk.w = v[6] | ((unsigned)v[7] << 16);
    *(uintx4*)(Bt + (size_t)n * K_PAD + kp0 + c * 8) = pk;
  }
}

// ---------------------------------------------------------------------------
// Split-K bf16 MFMA GEMM, A direct-to-register (no A LDS), B via async
// global_load_lds (16B) into an XOR-swizzled 16 KB LDS tile.
//
// Block = 256 threads (4 waves), tile 64(M) x 128(N) x 64(K). Wave w owns
// rows 16w..16w+15 x all 128 cols (8 acc tiles). Grid = 64 Mtiles x 16 K-chunks.
//
// Bs swizzle: logical (n, kc) chunk (16B, kc=0..7) stored at slot
// kc ^ (n&7) within row n. Staging lane l (of wave) deposits at LDS
// base+l*16 (HW constraint) and sources global chunk (l&7)^(l>>3) of row
// n = wave_row_base + (l>>3) -> exactly that swizzle. Frag ds_read_b128
// then lands 2 lanes per 16B slot per quad -> uniform bank load (free).
// ---------------------------------------------------------------------------
__global__ __launch_bounds__(256, 4)
void gemm_bf16_splitk(const float* __restrict__ A,
                      const unsigned short* __restrict__ Bt,
                      float* __restrict__ out){
  __shared__ __align__(16) unsigned short Bs[N_EMB * BK];   // 16 KB, swizzled

  const int tid   = threadIdx.x;
  const int bx    = blockIdx.x;
  const int mtile = bx & 63;
  const int s     = bx >> 6;
  const int m0    = mtile * BM;
  const int it0   = (s * IT_TOTAL) >> 4;
  const int it1   = ((s + 1) * IT_TOTAL) >> 4;

  const int lane = tid & 63;
  const int wv   = tid >> 6;
  const int col  = lane & 15;
  const int quad = lane >> 4;
  const int x    = col & 7;            // read-side swizzle key

  // B staging: 4 chunks of 16B per thread
  const int sl = (lane & 7) ^ (lane >> 3);      // source chunk (swizzle)
  const int nr = lane >> 3;                     // row within the 8-row group

  // A: this lane's private row
  const float* Arow = A + (size_t)(m0 + 16 * wv + col) * K_EFF;

  floatx4 acc[8];
#pragma unroll
  for (int c = 0; c < 8; ++c) acc[c] = (floatx4)0.0f;

  for (int it = it0; it < it1; ++it){
    const int kt = it * BK;
    __syncthreads();   // all waves done reading Bs from previous iter

    // ---- B: async DMA global->LDS, 16B per lane, swizzled source ----
#pragma unroll
    for (int p = 0; p < 4; ++p){
      const int n = (p * 4 + wv) * 8 + nr;
      const unsigned short* g = Bt + (size_t)n * K_PAD + kt + sl * 8;
      __builtin_amdgcn_global_load_lds(
          (const __attribute__((address_space(1))) void*)g,
          (__attribute__((address_space(3))) void*)(Bs + (p * 4 + wv) * 512),
          16, 0, 0);
    }

    // ---- A: direct global->register fragments (no LDS) ----
    float a[16];
    if (kt + BK <= K_EFF){
      const floatx2* ap = (const floatx2*)(Arow + kt + quad * 8);      // 8B aligned
      const floatx2* aq = (const floatx2*)(Arow + kt + 32 + quad * 8);
#pragma unroll
      for (int h = 0; h < 4; ++h){
        floatx2 u = __builtin_nontemporal_load(ap + h);
        floatx2 v = __builtin_nontemporal_load(aq + h);
        a[2 * h] = u.x; a[2 * h + 1] = u.y;
        a[8 + 2 * h] = v.x; a[8 + 2 * h + 1] = v.y;
      }
    } else {
      // ragged K tail (last iter of s==15 only)
#pragma unroll
      for (int j = 0; j < 8; ++j){
        const int k0 = kt + quad * 8 + j;
        const int k1 = k0 + 32;
        a[j]     = (k0 < K_EFF) ? Arow[k0] : 0.0f;
        a[8 + j] = (k1 < K_EFF) ? Arow[k1] : 0.0f;
      }
    }
    short8 af0, af1;
#pragma unroll
    for (int j = 0; j < 8; ++j){
      af0[j] = (short)f2bf(a[j]);
      af1[j] = (short)f2bf(a[8 + j]);
    }

    __syncthreads();   // DMA complete (vmcnt drain) + visible to all waves

    // ---- compute: 2 k-steps x 8 n-tiles ----
#pragma unroll
    for (int ks = 0; ks < 2; ++ks){
      const short8 af = ks ? af1 : af0;
      const int kc = ks * 4 + quad;              // logical 16B chunk 0..7
#pragma unroll
      for (int c = 0; c < 8; ++c){
        const int n = 16 * c + col;
        const short8 bf = *(const short8*)(Bs + n * 64 + ((kc ^ x) << 3));
        acc[c] = __builtin_amdgcn_mfma_f32_16x16x32_bf16(af, bf, acc[c], 0, 0, 0);
      }
    }
  }

  // ---- epilogue: C/D layout col=lane&15, row=quad*4+i; fp32 atomics ----
  const int rbase = m0 + 16 * wv + quad * 4;
#pragma unroll
  for (int c = 0; c < 8; ++c){
#pragma unroll
    for (int i = 0; i < 4; ++i){
      atomicAdd(out + (size_t)(rbase + i) * N_EMB + 16 * c + col, acc[c][i]);
    }
  }
}

extern "C" void kernel_launch(void* const* d_in, const int* in_sizes, int n_in,
                              void* d_out, int out_size, void* d_ws, size_t ws_size,
                              hipStream_t stream) {
  const float* A = (const float*)d_in[0];      // input_ [4096][49998] fp32
  const float* W = (const float*)d_in[1];      // word2vecs [50000][128] fp32
  float* out = (float*)d_out;                  // [4096][128] fp32
  unsigned short* Bt = (unsigned short*)d_ws;  // bf16 [128][K_PAD] = 12.8 MB

  prep_bt<<<dim3(K_PAD / 64), dim3(256), 0, stream>>>(W, Bt, out);
  gemm_bf16_splitk<<<dim3(64 * S_SPLIT), dim3(256), 0, stream>>>(A, Bt, out);
}